// Round 1
// baseline (673.965 us; speedup 1.0000x reference)
//
#include <hip/hip_runtime.h>

// Message passing: for each edge (s, d) with feature vector e_k:
//   out[d] += r[s] * e_k
//   out[s] += r[d] * e_k
// One thread per (edge, feature). D_FEAT = 128 fixed.

#define D_FEAT 128

__global__ void mp_scatter_kernel(const float* __restrict__ r,
                                  const float* __restrict__ e,
                                  const int* __restrict__ a,
                                  float* __restrict__ out,
                                  int n_edges) {
    long long gid = (long long)blockIdx.x * blockDim.x + threadIdx.x;
    int edge = (int)(gid >> 7);       // gid / 128
    int feat = (int)(gid & 127);      // gid % 128
    if (edge >= n_edges) return;

    int s = a[2 * edge];
    int d = a[2 * edge + 1];

    float ev = e[(long long)edge * D_FEAT + feat];
    float rs = r[(long long)s * D_FEAT + feat];
    float rd = r[(long long)d * D_FEAT + feat];

    atomicAdd(&out[(long long)d * D_FEAT + feat], rs * ev);
    atomicAdd(&out[(long long)s * D_FEAT + feat], rd * ev);
}

extern "C" void kernel_launch(void* const* d_in, const int* in_sizes, int n_in,
                              void* d_out, int out_size, void* d_ws, size_t ws_size,
                              hipStream_t stream) {
    const float* r = (const float*)d_in[0];
    const float* e = (const float*)d_in[1];
    const int*   a = (const int*)d_in[2];
    float* out = (float*)d_out;

    int n_edges = in_sizes[1] / D_FEAT;   // e is [E, 128]

    // d_out is poisoned to 0xAA before every launch — zero it first.
    hipMemsetAsync(d_out, 0, (size_t)out_size * sizeof(float), stream);

    long long total = (long long)n_edges * D_FEAT;
    int block = 256;
    long long grid = (total + block - 1) / block;
    mp_scatter_kernel<<<(int)grid, block, 0, stream>>>(r, e, a, out, n_edges);
}

// Round 2
// 659.585 us; speedup vs baseline: 1.0218x; 1.0218x over previous
//
#include <hip/hip_runtime.h>

// Message passing, gather formulation.
// For edge e=(s,d): out[d] += r[s]*ev ; out[s] += r[d]*ev.
// Entry k in [0, 2E): edge = k>>1, j = k&1.
//   center = a[2*edge + (j^1)]   (row of out that accumulates)
//   other  = a[2*edge + j]       (row of r that is gathered)
// Build CSR (offsets + entry list sorted by center) in d_ws, then one wave
// per node accumulates its entries in registers -> single coalesced store.

#define D_FEAT 128
#define SCAN_THREADS 1024

__global__ void hist_kernel(const int* __restrict__ a, int* __restrict__ deg,
                            int n_elems) {
    int i = blockIdx.x * blockDim.x + threadIdx.x;
    if (i < n_elems) atomicAdd(&deg[a[i]], 1);
}

// Single-block exclusive scan over n_nodes counters.
// Writes exclusive prefix into offs[0..n] and into deg[] (cursor for fill).
__global__ void scan_kernel(int* __restrict__ deg, int* __restrict__ offs,
                            int n_nodes) {
    __shared__ int lds[SCAN_THREADS];
    int t = threadIdx.x;
    int chunk = (n_nodes + SCAN_THREADS - 1) / SCAN_THREADS;
    int base = t * chunk;
    int endi = min(base + chunk, n_nodes);
    int s = 0;
    for (int i = base; i < endi; ++i) s += deg[i];
    lds[t] = s;
    __syncthreads();
    // Hillis-Steele inclusive scan in LDS
    for (int off = 1; off < SCAN_THREADS; off <<= 1) {
        int v = (t >= off) ? lds[t - off] : 0;
        __syncthreads();
        lds[t] += v;
        __syncthreads();
    }
    int excl = (t == 0) ? 0 : lds[t - 1];
    int total = lds[SCAN_THREADS - 1];
    int p = excl;
    for (int i = base; i < endi; ++i) {
        int v = deg[i];
        offs[i] = p;
        deg[i] = p;   // cursor start for fill phase
        p += v;
    }
    if (t == 0) offs[n_nodes] = total;
}

__global__ void fill_kernel(const int* __restrict__ a, int* __restrict__ cursor,
                            int* __restrict__ list, int n_entries) {
    int k = blockIdx.x * blockDim.x + threadIdx.x;
    if (k >= n_entries) return;
    int edge = k >> 1, j = k & 1;
    int center = a[2 * edge + (j ^ 1)];
    int pos = atomicAdd(&cursor[center], 1);
    list[pos] = k;
}

__global__ __launch_bounds__(64) void gather_kernel(
    const float* __restrict__ r, const float* __restrict__ e,
    const int* __restrict__ a, const int* __restrict__ offs,
    const int* __restrict__ list, float* __restrict__ out) {
    int n = blockIdx.x;
    int lane = threadIdx.x;          // 0..63, covers feats 2*lane, 2*lane+1
    int start = offs[n];
    int end = offs[n + 1];
    float accx = 0.f, accy = 0.f;
    int i = start;
    for (; i + 2 <= end; i += 2) {
        int k0 = list[i];
        int k1 = list[i + 1];
        int e0 = k0 >> 1, j0 = k0 & 1;
        int e1 = k1 >> 1, j1 = k1 & 1;
        int o0 = a[2 * e0 + j0];
        int o1 = a[2 * e1 + j1];
        float2 ev0 = *(const float2*)(e + (size_t)e0 * D_FEAT + lane * 2);
        float2 rv0 = *(const float2*)(r + (size_t)o0 * D_FEAT + lane * 2);
        float2 ev1 = *(const float2*)(e + (size_t)e1 * D_FEAT + lane * 2);
        float2 rv1 = *(const float2*)(r + (size_t)o1 * D_FEAT + lane * 2);
        accx += ev0.x * rv0.x;
        accy += ev0.y * rv0.y;
        accx += ev1.x * rv1.x;
        accy += ev1.y * rv1.y;
    }
    if (i < end) {
        int k0 = list[i];
        int e0 = k0 >> 1, j0 = k0 & 1;
        int o0 = a[2 * e0 + j0];
        float2 ev0 = *(const float2*)(e + (size_t)e0 * D_FEAT + lane * 2);
        float2 rv0 = *(const float2*)(r + (size_t)o0 * D_FEAT + lane * 2);
        accx += ev0.x * rv0.x;
        accy += ev0.y * rv0.y;
    }
    float2 res;
    res.x = accx;
    res.y = accy;
    *(float2*)(out + (size_t)n * D_FEAT + lane * 2) = res;
}

// ---- fallback (round-1 atomic scatter) if ws too small ----
__global__ void mp_scatter_kernel(const float* __restrict__ r,
                                  const float* __restrict__ e,
                                  const int* __restrict__ a,
                                  float* __restrict__ out,
                                  int n_edges) {
    long long gid = (long long)blockIdx.x * blockDim.x + threadIdx.x;
    int edge = (int)(gid >> 7);
    int feat = (int)(gid & 127);
    if (edge >= n_edges) return;
    int s = a[2 * edge];
    int d = a[2 * edge + 1];
    float ev = e[(long long)edge * D_FEAT + feat];
    float rs = r[(long long)s * D_FEAT + feat];
    float rd = r[(long long)d * D_FEAT + feat];
    atomicAdd(&out[(long long)d * D_FEAT + feat], rs * ev);
    atomicAdd(&out[(long long)s * D_FEAT + feat], rd * ev);
}

extern "C" void kernel_launch(void* const* d_in, const int* in_sizes, int n_in,
                              void* d_out, int out_size, void* d_ws, size_t ws_size,
                              hipStream_t stream) {
    const float* r = (const float*)d_in[0];
    const float* e = (const float*)d_in[1];
    const int*   a = (const int*)d_in[2];
    float* out = (float*)d_out;

    int n_nodes   = in_sizes[0] / D_FEAT;
    int n_edges   = in_sizes[1] / D_FEAT;
    int n_entries = 2 * n_edges;           // == in_sizes[2]

    size_t need = ((size_t)n_nodes + (size_t)(n_nodes + 1) + (size_t)n_entries)
                  * sizeof(int);
    if (ws_size < need) {
        // fallback: atomic scatter (round-1 path)
        hipMemsetAsync(d_out, 0, (size_t)out_size * sizeof(float), stream);
        long long total = (long long)n_edges * D_FEAT;
        int block = 256;
        long long grid = (total + block - 1) / block;
        mp_scatter_kernel<<<(int)grid, block, 0, stream>>>(r, e, a, out, n_edges);
        return;
    }

    int* deg  = (int*)d_ws;                // N (cursor after scan)
    int* offs = deg + n_nodes;             // N+1
    int* list = offs + n_nodes + 1;        // 2E

    hipMemsetAsync(deg, 0, (size_t)n_nodes * sizeof(int), stream);

    int block = 256;
    int grid_e = (n_entries + block - 1) / block;
    hist_kernel<<<grid_e, block, 0, stream>>>(a, deg, n_entries);
    scan_kernel<<<1, SCAN_THREADS, 0, stream>>>(deg, offs, n_nodes);
    fill_kernel<<<grid_e, block, 0, stream>>>(a, deg, list, n_entries);
    gather_kernel<<<n_nodes, 64, 0, stream>>>(r, e, a, offs, list, out);
}